// Round 3
// baseline (1116.455 us; speedup 1.0000x reference)
//
#include <hip/hip_runtime.h>

// Transformer layer, bf16 MFMA compute, fp32 I/O.
// B=2 T=2048 E=2048 H=16 DH=128 FFN=8192. Needs ~235MB workspace.

#define T_SEQ 2048
#define E_DIM 2048
#define N_HEAD 16
#define D_HEAD 128
#define FFN_DIM 8192
#define M_ROWS 4096  // B*T

typedef unsigned short u16;
typedef short short8 __attribute__((ext_vector_type(8)));
typedef float f32x4 __attribute__((ext_vector_type(4)));

#define DEV __device__ __forceinline__

DEV u16 f2bf(float f) {
  unsigned u = __float_as_uint(f);
  u += 0x7fffu + ((u >> 16) & 1u);
  return (u16)(u >> 16);
}
DEV float bf2f(u16 h) { return __uint_as_float(((unsigned)h) << 16); }

DEV void async16(void* lds, const void* g) {
  __builtin_amdgcn_global_load_lds((const __attribute__((address_space(1))) void*)g,
                                   (__attribute__((address_space(3))) void*)lds, 16, 0, 0);
}

// ---------------- LayerNorm: fp32 [rows][E] -> bf16 -----------------
__global__ __launch_bounds__(256) void ln_kernel(const float* __restrict__ x,
                                                 const float* __restrict__ gw,
                                                 const float* __restrict__ bw,
                                                 u16* __restrict__ out) {
  int row = blockIdx.x;
  int t = threadIdx.x;
  const float4* xr = (const float4*)(x + (size_t)row * E_DIM);
  float4 a = xr[t], c = xr[t + 256];
  float s = a.x + a.y + a.z + a.w + c.x + c.y + c.z + c.w;
  float q = a.x * a.x + a.y * a.y + a.z * a.z + a.w * a.w +
            c.x * c.x + c.y * c.y + c.z * c.z + c.w * c.w;
  for (int off = 32; off > 0; off >>= 1) {
    s += __shfl_down(s, off);
    q += __shfl_down(q, off);
  }
  __shared__ float red[8];
  if ((t & 63) == 0) { red[(t >> 6) * 2] = s; red[(t >> 6) * 2 + 1] = q; }
  __syncthreads();
  s = red[0] + red[2] + red[4] + red[6];
  q = red[1] + red[3] + red[5] + red[7];
  float mu = s * (1.f / E_DIM);
  float rs = rsqrtf(q * (1.f / E_DIM) - mu * mu + 1e-5f);
  const float4* g4 = (const float4*)gw;
  const float4* b4 = (const float4*)bw;
  float4 g0 = g4[t], g1v = g4[t + 256], e0 = b4[t], e1 = b4[t + 256];
  ushort4 o0, o1;
  o0.x = f2bf((a.x - mu) * rs * g0.x + e0.x);
  o0.y = f2bf((a.y - mu) * rs * g0.y + e0.y);
  o0.z = f2bf((a.z - mu) * rs * g0.z + e0.z);
  o0.w = f2bf((a.w - mu) * rs * g0.w + e0.w);
  o1.x = f2bf((c.x - mu) * rs * g1v.x + e1.x);
  o1.y = f2bf((c.y - mu) * rs * g1v.y + e1.y);
  o1.z = f2bf((c.z - mu) * rs * g1v.z + e1.z);
  o1.w = f2bf((c.w - mu) * rs * g1v.w + e1.w);
  ((ushort4*)(out + (size_t)row * E_DIM))[t] = o0;
  ((ushort4*)(out + (size_t)row * E_DIM))[t + 256] = o1;
}

// ------- convert+transpose: fp32 W[K][N] -> bf16 WT[N][K] -----------
__global__ __launch_bounds__(256) void cvt_t_kernel(const float* __restrict__ W,
                                                    u16* __restrict__ WT,
                                                    int Kd, int Nd) {
  __shared__ float tile[32][33];
  int tx = threadIdx.x, ty = threadIdx.y;
  int n0 = blockIdx.x * 32, k0 = blockIdx.y * 32;
#pragma unroll
  for (int i = 0; i < 4; i++)
    tile[ty + i * 8][tx] = W[(size_t)(k0 + ty + i * 8) * Nd + n0 + tx];
  __syncthreads();
#pragma unroll
  for (int i = 0; i < 4; i++)
    WT[(size_t)(n0 + ty + i * 8) * Kd + k0 + tx] = f2bf(tile[tx][ty + i * 8]);
}

// ------- transpose V per batch: bf16 [B*T][E] -> [B][E][T] ----------
__global__ __launch_bounds__(256) void transpose_v_kernel(const u16* __restrict__ v,
                                                          u16* __restrict__ vt) {
  __shared__ u16 tile[32][33];
  int tx = threadIdx.x, ty = threadIdx.y;
  int b = blockIdx.z;
  int t0 = blockIdx.x * 32, e0 = blockIdx.y * 32;
#pragma unroll
  for (int i = 0; i < 4; i++)
    tile[ty + i * 8][tx] = v[(size_t)(b * T_SEQ + t0 + ty + i * 8) * E_DIM + e0 + tx];
  __syncthreads();
#pragma unroll
  for (int i = 0; i < 4; i++)
    vt[((size_t)b * E_DIM + e0 + ty + i * 8) * T_SEQ + t0 + tx] = tile[tx][ty + i * 8];
}

// ============ GEMM 128x256xBK64, 512 thr (8 waves 2Mx4N) ============
// C[M][N] = A[M][K] * BT[N][K]^T.  Double-buffered LDS (96KB),
// T2 chunk^=(row&7) swizzle (pre-swizzled global src, linear LDS dst),
// T4 counted vmcnt(6) (loads span barriers; drain only on last tile),
// T5 setprio around MFMA cluster, T1 bijective XCD swizzle.
// MODE 0: bf16 C.  MODE 1: Cout(f32) = Extra(f32) + acc.
// MODE 2: Cout(bf16) = silu(Extra bf16) * acc (Extra may alias Cout).
template <int MODE>
__global__ __launch_bounds__(512, 2) void gemm256(const u16* __restrict__ A,
                                                  const u16* __restrict__ BT,
                                                  void* Cout, const void* Extra,
                                                  int N, int K, int colMajorXcd) {
  __shared__ u16 As0[128 * 64], As1[128 * 64];
  __shared__ u16 Bs0[256 * 64], Bs1[256 * 64];
  const int t = threadIdx.x;
  const int w = t >> 6, l = t & 63;
  const int g = l >> 4, lq = l & 15;
  const int wm = w >> 2, wn = w & 3;

  // ---- bijective XCD swizzle (nwg % 8 == 0 for all our shapes) ----
  const int gx = gridDim.x, gy = gridDim.y;
  const int nwg = gx * gy;
  int lin = colMajorXcd ? (blockIdx.x * gy + blockIdx.y)
                        : (blockIdx.y * gx + blockIdx.x);
  const int q = nwg >> 3;
  int wg = (lin & 7) * q + (lin >> 3);
  int bx, by;
  if (colMajorXcd) { bx = wg / gy; by = wg - bx * gy; }
  else             { by = wg / gx; bx = wg - by * gx; }
  const size_t bm = (size_t)by * 128, bn = (size_t)bx * 256;

  // ---- staging addresses (pre-swizzled global source, rule #21) ----
  const int srow = l >> 3;                       // 0..7
  const int schunk = ((l & 7) ^ srow) << 3;      // element offset in row
  const u16* Asrc = A + (bm + 8 * w + srow) * (size_t)K + schunk;
  const u16* Bsrc = BT + (bn + 8 * w + srow) * (size_t)K + schunk;

#define STAGE_TILE(CC, KT)                                              \
  {                                                                     \
    u16* Ad = ((CC) ? As1 : As0) + w * 512;                             \
    u16* Bd = ((CC) ? Bs1 : Bs0) + w * 512;                             \
    size_t ko = (size_t)(KT) * 64;                                      \
    async16(Ad, Asrc + ko);                                             \
    async16(Ad + 4096, Asrc + (size_t)64 * K + ko);                     \
    async16(Bd, Bsrc + ko);                                             \
    async16(Bd + 4096, Bsrc + (size_t)64 * K + ko);                     \
    async16(Bd + 8192, Bsrc + (size_t)128 * K + ko);                    \
    async16(Bd + 12288, Bsrc + (size_t)192 * K + ko);                   \
  }

  const int NT = K >> 6;
  STAGE_TILE(0, 0);
  STAGE_TILE(1, 1);

  f32x4 acc[4][4] = {};

  for (int kt = 0; kt < NT; ++kt) {
    const int c = kt & 1;
    if (kt + 1 < NT) asm volatile("s_waitcnt vmcnt(6)" ::: "memory");
    else             asm volatile("s_waitcnt vmcnt(0)" ::: "memory");
    asm volatile("s_barrier" ::: "memory");

    const u16* Ab = c ? As1 : As0;
    const u16* Bb = c ? Bs1 : Bs0;
    short8 af[2][4], bf[2][4];
#pragma unroll
    for (int ks = 0; ks < 2; ks++) {
#pragma unroll
      for (int m = 0; m < 4; m++)
        af[ks][m] = *(const short8*)(Ab + (wm * 64 + m * 16 + lq) * 64 +
                                     (((ks * 4 + g) ^ (lq & 7)) << 3));
#pragma unroll
      for (int n = 0; n < 4; n++)
        bf[ks][n] = *(const short8*)(Bb + (wn * 64 + n * 16 + lq) * 64 +
                                     (((ks * 4 + g) ^ (lq & 7)) << 3));
    }
    __builtin_amdgcn_s_setprio(1);
#pragma unroll
    for (int ks = 0; ks < 2; ks++)
#pragma unroll
      for (int m = 0; m < 4; m++)
#pragma unroll
        for (int n = 0; n < 4; n++)
          acc[m][n] = __builtin_amdgcn_mfma_f32_16x16x32_bf16(af[ks][m], bf[ks][n],
                                                              acc[m][n], 0, 0, 0);
    __builtin_amdgcn_s_setprio(0);
    // all LDS reads must be serviced before staging may overwrite (#18)
    __builtin_amdgcn_sched_barrier(0);
    asm volatile("s_waitcnt lgkmcnt(0)" ::: "memory");
    asm volatile("s_barrier" ::: "memory");
    if (kt + 2 < NT) STAGE_TILE(c, kt + 2);
  }
#undef STAGE_TILE

#pragma unroll
  for (int m = 0; m < 4; m++) {
    size_t row = bm + wm * 64 + m * 16 + 4 * g;
#pragma unroll
    for (int n = 0; n < 4; n++) {
      size_t col = bn + wn * 64 + n * 16 + lq;
#pragma unroll
      for (int r = 0; r < 4; r++) {
        size_t idx = (row + r) * (size_t)N + col;
        if constexpr (MODE == 0) {
          ((u16*)Cout)[idx] = f2bf(acc[m][n][r]);
        } else if constexpr (MODE == 1) {
          ((float*)Cout)[idx] = ((const float*)Extra)[idx] + acc[m][n][r];
        } else {
          float a = bf2f(((const u16*)Extra)[idx]);
          float sil = a / (1.f + exp2f(-1.4426950408889634f * a));
          ((u16*)Cout)[idx] = f2bf(sil * acc[m][n][r]);
        }
      }
    }
  }
}

// ----------------- causal flash attention (LDS-staged) --------------
// grid (T/64, B*H); 4 waves/block; block owns 64 q-rows of one (b,h);
// wave w owns rows q0blk + 16w .. +16.  KV tile = 64.
__global__ __launch_bounds__(256, 3) void attn_kernel(const u16* __restrict__ Q,
                                                      const u16* __restrict__ Kb,
                                                      const u16* __restrict__ VT,
                                                      u16* __restrict__ CTX) {
  __shared__ u16 Ks[64 * 128];    // 16 KB
  __shared__ u16 Vs[128 * 64];    // 16 KB
  __shared__ u16 P_all[4][16 * 72];  // 9 KB, per-wave padded P tile
  const int t = threadIdx.x;
  const int w = t >> 6, l = t & 63, g = l >> 4, lq = l & 15;
  u16* P = P_all[w];
  const int q0blk = blockIdx.x * 64;
  const int q0w = q0blk + w * 16;
  const int bh = blockIdx.y, b = bh >> 4, h = bh & 15;
  const u16* qp = Q + (size_t)b * T_SEQ * E_DIM + h * D_HEAD;
  const u16* kp = Kb + (size_t)b * T_SEQ * E_DIM + h * D_HEAD;
  const u16* vp = VT + ((size_t)b * E_DIM + h * D_HEAD) * T_SEQ;

  short8 qf[4];
#pragma unroll
  for (int ks = 0; ks < 4; ks++)
    qf[ks] = *(const short8*)(qp + (size_t)(q0w + lq) * E_DIM + ks * 32 + g * 8);

  f32x4 acc[8] = {};
  float m2[4], ls[4];
#pragma unroll
  for (int r = 0; r < 4; r++) { m2[r] = -1e30f; ls[r] = 0.f; }
  const float sc = 0.08838834764831845f * 1.4426950408889634f;  // 1/sqrt(128)*log2e

  const int kRow0 = 16 * w + (l >> 4);
  const int kChunk = l & 15;
  const int vRow0 = 32 * w + (l >> 3);
  const int vChunk = l & 7;

  for (int kv0 = 0; kv0 <= q0blk; kv0 += 64) {
#pragma unroll
    for (int j = 0; j < 4; j++) {
      int R = kRow0 + 4 * j;
      async16(Ks + (16 * w + 4 * j) * 128,
              kp + (size_t)(kv0 + R) * E_DIM + ((kChunk ^ (R & 7)) << 3));
    }
#pragma unroll
    for (int j = 0; j < 4; j++) {
      int D = vRow0 + 8 * j;
      async16(Vs + (32 * w + 8 * j) * 64,
              vp + (size_t)D * T_SEQ + kv0 + ((vChunk ^ (D & 7)) << 3));
    }
    __syncthreads();

    f32x4 s[4];
#pragma unroll
    for (int ct = 0; ct < 4; ct++) {
      s[ct] = f32x4{0.f, 0.f, 0.f, 0.f};
#pragma unroll
      for (int ks = 0; ks < 4; ks++) {
        short8 kf = *(const short8*)(Ks + (ct * 16 + lq) * 128 +
                                     (((ks * 4 + g) ^ (lq & 7)) << 3));
        s[ct] = __builtin_amdgcn_mfma_f32_16x16x32_bf16(qf[ks], kf, s[ct], 0, 0, 0);
      }
    }
    float sv[4][4];
#pragma unroll
    for (int ct = 0; ct < 4; ct++)
#pragma unroll
      for (int r = 0; r < 4; r++) sv[ct][r] = s[ct][r] * sc;
    if (kv0 + 64 > q0w) {
#pragma unroll
      for (int ct = 0; ct < 4; ct++)
#pragma unroll
        for (int r = 0; r < 4; r++)
          if (kv0 + ct * 16 + lq > q0w + 4 * g + r) sv[ct][r] = -1e30f;
    }
    float mx[4];
#pragma unroll
    for (int r = 0; r < 4; r++)
      mx[r] = fmaxf(fmaxf(sv[0][r], sv[1][r]), fmaxf(sv[2][r], sv[3][r]));
#pragma unroll
    for (int off = 1; off < 16; off <<= 1)
#pragma unroll
      for (int r = 0; r < 4; r++) mx[r] = fmaxf(mx[r], __shfl_xor(mx[r], off));
#pragma unroll
    for (int r = 0; r < 4; r++) {
      float mn = fmaxf(m2[r], mx[r]);
      float sca = exp2f(m2[r] - mn);
      m2[r] = mn;
      float sum = 0.f;
#pragma unroll
      for (int ct = 0; ct < 4; ct++) {
        float pv = exp2f(sv[ct][r] - mn);
        sum += pv;
        P[(4 * g + r) * 72 + ct * 16 + lq] = f2bf(pv);
      }
      ls[r] = ls[r] * sca + sum;
#pragma unroll
      for (int n = 0; n < 8; n++) acc[n][r] *= sca;
    }
    short8 pa[2];
#pragma unroll
    for (int ks2 = 0; ks2 < 2; ks2++)
      pa[ks2] = *(const short8*)(P + lq * 72 + ks2 * 32 + g * 8);
#pragma unroll
    for (int n = 0; n < 8; n++)
#pragma unroll
      for (int ks2 = 0; ks2 < 2; ks2++) {
        short8 vf = *(const short8*)(Vs + (n * 16 + lq) * 64 +
                                     (((ks2 * 4 + g) ^ (lq & 7)) << 3));
        acc[n] = __builtin_amdgcn_mfma_f32_16x16x32_bf16(pa[ks2], vf, acc[n], 0, 0, 0);
      }
    __syncthreads();
  }

#pragma unroll
  for (int off = 1; off < 16; off <<= 1)
#pragma unroll
    for (int r = 0; r < 4; r++) ls[r] += __shfl_xor(ls[r], off);
  float inv[4];
#pragma unroll
  for (int r = 0; r < 4; r++) inv[r] = 1.f / ls[r];
  u16* cp = CTX + ((size_t)b * T_SEQ + q0w) * E_DIM + h * D_HEAD;
#pragma unroll
  for (int n = 0; n < 8; n++)
#pragma unroll
    for (int r = 0; r < 4; r++)
      cp[(size_t)(4 * g + r) * E_DIM + n * 16 + lq] = f2bf(acc[n][r] * inv[r]);
}

extern "C" void kernel_launch(void* const* d_in, const int* in_sizes, int n_in,
                              void* d_out, int out_size, void* d_ws, size_t ws_size,
                              hipStream_t stream) {
  (void)in_sizes; (void)n_in; (void)out_size; (void)ws_size;
  const float* x  = (const float*)d_in[0];
  const float* g1 = (const float*)d_in[1];
  const float* b1 = (const float*)d_in[2];
  const float* wq = (const float*)d_in[3];
  const float* wk = (const float*)d_in[4];
  const float* wv = (const float*)d_in[5];
  const float* wo = (const float*)d_in[6];
  const float* g2 = (const float*)d_in[7];
  const float* b2 = (const float*)d_in[8];
  const float* w1 = (const float*)d_in[9];
  const float* w2 = (const float*)d_in[10];
  const float* w3 = (const float*)d_in[11];
  float* out = (float*)d_out;

  const size_t EE2 = (size_t)E_DIM * E_DIM * 2;
  const size_t EF2 = (size_t)E_DIM * FFN_DIM * 2;
  const size_t ME2 = (size_t)M_ROWS * E_DIM * 2;
  char* p = (char*)d_ws;
  u16* wqT = (u16*)p; p += EE2;
  u16* wkT = (u16*)p; p += EE2;
  u16* wvT = (u16*)p; p += EE2;
  u16* woT = (u16*)p; p += EE2;
  u16* w1T = (u16*)p; p += EF2;
  u16* w2T = (u16*)p; p += EF2;
  u16* w3T = (u16*)p; p += EF2;
  u16* Hb  = (u16*)p; p += ME2;
  u16* Qb  = (u16*)p; p += ME2;
  u16* Kbf = (u16*)p; p += ME2;
  u16* Vb  = (u16*)p; p += ME2;
  u16* VTb = (u16*)p; p += ME2;
  u16* CTXb = (u16*)p; p += ME2;
  u16* U1b = Qb;  // u1/gated (67MB) reuses dead q/k/v/vT region

  dim3 blk32(32, 8);
  // weights -> bf16 transposed [N][K]
  cvt_t_kernel<<<dim3(E_DIM / 32, E_DIM / 32), blk32, 0, stream>>>(wq, wqT, E_DIM, E_DIM);
  cvt_t_kernel<<<dim3(E_DIM / 32, E_DIM / 32), blk32, 0, stream>>>(wk, wkT, E_DIM, E_DIM);
  cvt_t_kernel<<<dim3(E_DIM / 32, E_DIM / 32), blk32, 0, stream>>>(wv, wvT, E_DIM, E_DIM);
  cvt_t_kernel<<<dim3(E_DIM / 32, E_DIM / 32), blk32, 0, stream>>>(wo, woT, E_DIM, E_DIM);
  cvt_t_kernel<<<dim3(FFN_DIM / 32, E_DIM / 32), blk32, 0, stream>>>(w1, w1T, E_DIM, FFN_DIM);
  cvt_t_kernel<<<dim3(FFN_DIM / 32, E_DIM / 32), blk32, 0, stream>>>(w2, w2T, E_DIM, FFN_DIM);
  cvt_t_kernel<<<dim3(E_DIM / 32, FFN_DIM / 32), blk32, 0, stream>>>(w3, w3T, FFN_DIM, E_DIM);

  // attention block
  ln_kernel<<<M_ROWS, 256, 0, stream>>>(x, g1, b1, Hb);
  gemm256<0><<<dim3(E_DIM / 256, M_ROWS / 128), 512, 0, stream>>>(Hb, wqT, Qb, nullptr, E_DIM, E_DIM, 0);
  gemm256<0><<<dim3(E_DIM / 256, M_ROWS / 128), 512, 0, stream>>>(Hb, wkT, Kbf, nullptr, E_DIM, E_DIM, 0);
  gemm256<0><<<dim3(E_DIM / 256, M_ROWS / 128), 512, 0, stream>>>(Hb, wvT, Vb, nullptr, E_DIM, E_DIM, 0);
  transpose_v_kernel<<<dim3(T_SEQ / 32, E_DIM / 32, 2), blk32, 0, stream>>>(Vb, VTb);
  attn_kernel<<<dim3(T_SEQ / 64, 2 * N_HEAD), 256, 0, stream>>>(Qb, Kbf, VTb, CTXb);
  gemm256<1><<<dim3(E_DIM / 256, M_ROWS / 128), 512, 0, stream>>>(CTXb, woT, out, x, E_DIM, E_DIM, 0);

  // SwiGLU MLP block
  ln_kernel<<<M_ROWS, 256, 0, stream>>>(out, g2, b2, Hb);
  gemm256<0><<<dim3(FFN_DIM / 256, M_ROWS / 128), 512, 0, stream>>>(Hb, w1T, U1b, nullptr, FFN_DIM, E_DIM, 1);
  gemm256<2><<<dim3(FFN_DIM / 256, M_ROWS / 128), 512, 0, stream>>>(Hb, w2T, U1b, U1b, FFN_DIM, E_DIM, 1);
  gemm256<1><<<dim3(E_DIM / 256, M_ROWS / 128), 512, 0, stream>>>(U1b, w3T, out, out, E_DIM, FFN_DIM, 0);
}